// Round 3
// baseline (8110.366 us; speedup 1.0000x reference)
//
#include <hip/hip_runtime.h>
#include <hip/hip_bf16.h>

#define EPSV 1e-5f

// workspace float offsets
#define WS_SUM0   0
#define WS_SSQ0   64
#define WS_SUM1   128
#define WS_SSQ1   192
#define WS_SUM2   256
#define WS_SSQ2   320
#define WS_AL0    384
#define WS_BE0    448
#define WS_ZBG    512
#define WS_T1BG   576      // 64*32
#define WS_AL1    2624
#define WS_BE1    2688
#define WS_T2BG   2752     // 64*16
#define WS_AL2    3776
#define WS_BE2    3840
#define WS_A2BG   3904     // 64*16
#define WS_OC     4928     // 9 used

// Repacked conv weights in LDS: only di,dj in [0,3] reachable (r,s <= 3).
// Layout: sW[k*81 + cc*16 + di*4 + dj]  (stride 81 -> odd vs 32 banks)
#define CONV_LDS 5184

__device__ __forceinline__ void stage_conv(float* sW, const float* __restrict__ conv_w,
                                           int nthr) {
  for (int i = threadIdx.x; i < 8000; i += nthr) {
    int k = i / 125, rem = i - k * 125;
    int cc = rem / 25, r2 = rem - cc * 25;
    int di = r2 / 5, dj = r2 - di * 5;
    if (di < 4 && dj < 4) sW[k * 81 + cc * 16 + di * 4 + dj] = conv_w[i];
  }
}

// ---------------------------------------------------------------------------
// Kernel 1: BN0 statistics over the active 16 conv positions (y<4, x<4).
// Wave-independent; atomics at end.
__global__ __launch_bounds__(256) void k_stats0(
    const int* __restrict__ x, const float* __restrict__ conv_w,
    const float* __restrict__ conv_b, float* __restrict__ ws, int M) {
  __shared__ float sW[CONV_LDS];
  stage_conv(sW, conv_w, 256);
  __syncthreads();
  const int tid = threadIdx.x;
  const int mg = tid & 3;
  const int k  = tid >> 2;
  const float cb = conv_b[k];
  const float* Wk = &sW[k * 81];
  float s = 0.f, ss = 0.f;
  for (int m = blockIdx.x * 4 + mg; m < M; m += gridDim.x * 4) {
    int r[5], c[5];
    const int2* xp = (const int2*)(x + m * 10);
#pragma unroll
    for (int cc = 0; cc < 5; ++cc) { int2 t = xp[cc]; r[cc] = t.x; c[cc] = t.y; }
#pragma unroll
    for (int y = 0; y < 4; ++y) {
#pragma unroll
      for (int xx = 0; xx < 4; ++xx) {
        float v = cb;
#pragma unroll
        for (int cc = 0; cc < 5; ++cc) {
          int di = r[cc] - y, dj = c[cc] - xx;
          if ((di | dj) >= 0) v += Wk[cc * 16 + di * 4 + dj];
        }
        s += v;
        ss += v * v;
      }
      __builtin_amdgcn_sched_barrier(0);
    }
  }
  s  += __shfl_xor(s, 1);  s  += __shfl_xor(s, 2);
  ss += __shfl_xor(ss, 1); ss += __shfl_xor(ss, 2);
  if (mg == 0) {
    atomicAdd(&ws[WS_SUM0 + k], s);
    atomicAdd(&ws[WS_SSQ0 + k], ss);
  }
}

// ---------------------------------------------------------------------------
// Kernel 2: finalize BN0; background chain r1_bg -> t1_bg; seed BN1 stats.
__global__ __launch_bounds__(64) void k_fin0(
    const float* __restrict__ conv_b, const float* __restrict__ g0,
    const float* __restrict__ b0, const float* __restrict__ w_rank,
    const float* __restrict__ b_rank, const float* __restrict__ w_h1,
    const float* __restrict__ b_h1, float* __restrict__ ws, int M) {
  __shared__ float sS[32];
  const int t = threadIdx.x;
  if (t < 32) {
    float su = 0.f;
    for (int s2 = 0; s2 < 10; ++s2) su += w_rank[t * 10 + s2];
    sS[t] = su;
  }
  __syncthreads();
  const int k = t;
  const float n0 = 110.f * (float)M;
  const float cb = conv_b[k];
  const float S  = ws[WS_SUM0 + k] + 94.f * (float)M * cb;
  const float SS = ws[WS_SSQ0 + k] + 94.f * (float)M * cb * cb;
  const float mu = S / n0;
  const float var = SS / n0 - mu * mu;
  const float rstd = rsqrtf(var + EPSV);
  const float al = rstd * g0[k];
  const float be = b0[k] - mu * al;
  ws[WS_AL0 + k] = al;
  ws[WS_BE0 + k] = be;
  const float zbg = fmaxf(cb * al + be, 0.f);
  ws[WS_ZBG + k] = zbg;
  float r1bg[32];
#pragma unroll
  for (int o = 0; o < 32; ++o) r1bg[o] = fmaxf(zbg * sS[o] + b_rank[o], 0.f);
  float sb = 0.f, ssb = 0.f;
  for (int o = 0; o < 32; ++o) {
    float acc = b_h1[o];
#pragma unroll
    for (int i = 0; i < 32; ++i) acc += r1bg[i] * w_h1[o * 32 + i];
    ws[WS_T1BG + k * 32 + o] = acc;
    sb += acc;
    ssb += acc * acc;
  }
  ws[WS_SUM1 + k] = 7.f * (float)M * sb;
  ws[WS_SSQ1 + k] = 7.f * (float)M * ssb;
}

// ---------------------------------------------------------------------------
// Kernel 3: BN1 statistics. One WAVE per m (grid-stride), no block syncs.
// lane = (y = lane&3, k4 = lane>>2); 4 rows per lane (k = k4 + 16*rr).
__global__ __launch_bounds__(256) void k_stats1(
    const int* __restrict__ x, const float* __restrict__ conv_w,
    const float* __restrict__ conv_b, const float* __restrict__ w_rank,
    const float* __restrict__ b_rank, const float* __restrict__ w_h1,
    const float* __restrict__ b_h1, float* __restrict__ ws, int M) {
  __shared__ float sW[CONV_LDS];
  __shared__ float sWr[320], sBr[32], sCr[32];
  __shared__ float sW1[1024], sB1[32];
  stage_conv(sW, conv_w, 256);
  for (int i = threadIdx.x; i < 320; i += 256) sWr[i] = w_rank[i];
  for (int i = threadIdx.x; i < 1024; i += 256) sW1[i] = w_h1[i];
  if (threadIdx.x < 32) {
    sBr[threadIdx.x] = b_rank[threadIdx.x];
    sB1[threadIdx.x] = b_h1[threadIdx.x];
    float cu = 0.f;
    for (int s2 = 4; s2 < 10; ++s2) cu += w_rank[threadIdx.x * 10 + s2];
    sCr[threadIdx.x] = cu;
  }
  __syncthreads();
  const int tid = threadIdx.x;
  const int lane = tid & 63;
  const int y = lane & 3, k4 = lane >> 2;
  const int waveId = blockIdx.x * 4 + (tid >> 6);
  const int nW = gridDim.x * 4;
  float cbr[4], alr[4], ber[4], zbr[4];
#pragma unroll
  for (int rr = 0; rr < 4; ++rr) {
    const int k = k4 + 16 * rr;
    cbr[rr] = conv_b[k];
    alr[rr] = ws[WS_AL0 + k];
    ber[rr] = ws[WS_BE0 + k];
    zbr[rr] = ws[WS_ZBG + k];
  }
  float sAcc[4] = {0.f, 0.f, 0.f, 0.f}, ssAcc[4] = {0.f, 0.f, 0.f, 0.f};
  for (int m = waveId; m < M; m += nW) {
    int r[5], c[5];
    const int2* xp = (const int2*)(x + m * 10);
#pragma unroll
    for (int cc = 0; cc < 5; ++cc) { int2 t = xp[cc]; r[cc] = t.x; c[cc] = t.y; }
#pragma unroll
    for (int rr = 0; rr < 4; ++rr) {
      const int k = k4 + 16 * rr;
      const float* Wk = &sW[k * 81];
      const float al = alr[rr], be = ber[rr], zbg = zbr[rr], cb = cbr[rr];
      float a0[4];
#pragma unroll
      for (int xx = 0; xx < 4; ++xx) {
        float v = cb;
#pragma unroll
        for (int cc = 0; cc < 5; ++cc) {
          int di = r[cc] - y, dj = c[cc] - xx;
          if ((di | dj) >= 0) v += Wk[cc * 16 + di * 4 + dj];
        }
        a0[xx] = fmaxf(al * v + be, 0.f);
      }
      __builtin_amdgcn_sched_barrier(0);
      float r1[32];
#pragma unroll
      for (int o = 0; o < 32; ++o) {
        float acc = sBr[o] + zbg * sCr[o];
#pragma unroll
        for (int xx = 0; xx < 4; ++xx) acc += a0[xx] * sWr[o * 10 + xx];
        r1[o] = fmaxf(acc, 0.f);
      }
      __builtin_amdgcn_sched_barrier(0);
      float s1 = 0.f, ss1 = 0.f;
#pragma unroll
      for (int ch = 0; ch < 4; ++ch) {
#pragma unroll
        for (int u = 0; u < 8; ++u) {
          const int o = ch * 8 + u;
          float acc = sB1[o];
#pragma unroll
          for (int i = 0; i < 32; ++i) acc += r1[i] * sW1[o * 32 + i];
          s1 += acc;
          ss1 += acc * acc;
        }
        __builtin_amdgcn_sched_barrier(0);
      }
      sAcc[rr] += s1;
      ssAcc[rr] += ss1;
    }
  }
#pragma unroll
  for (int rr = 0; rr < 4; ++rr) {
    float s = sAcc[rr], ss = ssAcc[rr];
    s  += __shfl_xor(s, 1);  s  += __shfl_xor(s, 2);
    ss += __shfl_xor(ss, 1); ss += __shfl_xor(ss, 2);
    if (y == 0) {
      atomicAdd(&ws[WS_SUM1 + k4 + 16 * rr], s);
      atomicAdd(&ws[WS_SSQ1 + k4 + 16 * rr], ss);
    }
  }
}

// ---------------------------------------------------------------------------
// Kernel 4: finalize BN1; background a1_bg -> t2_bg; seed BN2 stats.
__global__ __launch_bounds__(64) void k_fin1(
    const float* __restrict__ g1, const float* __restrict__ b1,
    const float* __restrict__ w_h2, const float* __restrict__ b_h2,
    float* __restrict__ ws, int M) {
  const int k = threadIdx.x;
  const float n1 = (float)M * 11.f * 32.f;
  const float S = ws[WS_SUM1 + k], SS = ws[WS_SSQ1 + k];
  const float mu = S / n1;
  const float var = SS / n1 - mu * mu;
  const float rstd = rsqrtf(var + EPSV);
  const float al = rstd * g1[k];
  const float be = b1[k] - mu * al;
  ws[WS_AL1 + k] = al;
  ws[WS_BE1 + k] = be;
  float a1bg[32];
#pragma unroll
  for (int o = 0; o < 32; ++o)
    a1bg[o] = fmaxf(al * ws[WS_T1BG + k * 32 + o] + be, 0.f);
  float sb = 0.f, ssb = 0.f;
  for (int p = 0; p < 16; ++p) {
    float acc = b_h2[p];
#pragma unroll
    for (int o = 0; o < 32; ++o) acc += a1bg[o] * w_h2[p * 32 + o];
    ws[WS_T2BG + k * 16 + p] = acc;
    sb += acc;
    ssb += acc * acc;
  }
  ws[WS_SUM2 + k] = 7.f * (float)M * sb;
  ws[WS_SSQ2 + k] = 7.f * (float)M * ssb;
}

// ---------------------------------------------------------------------------
// Kernel 5: BN2 statistics. Wave-per-m, chunked a1 -> t2.
__global__ __launch_bounds__(256) void k_stats2(
    const int* __restrict__ x, const float* __restrict__ conv_w,
    const float* __restrict__ conv_b, const float* __restrict__ w_rank,
    const float* __restrict__ b_rank, const float* __restrict__ w_h1,
    const float* __restrict__ b_h1, const float* __restrict__ w_h2,
    const float* __restrict__ b_h2, float* __restrict__ ws, int M) {
  __shared__ float sW[CONV_LDS];
  __shared__ float sWr[320], sBr[32], sCr[32];
  __shared__ float sW1[1024], sB1[32];
  __shared__ float sW2[512], sB2[16];
  stage_conv(sW, conv_w, 256);
  for (int i = threadIdx.x; i < 320; i += 256) sWr[i] = w_rank[i];
  for (int i = threadIdx.x; i < 1024; i += 256) sW1[i] = w_h1[i];
  for (int i = threadIdx.x; i < 512; i += 256) sW2[i] = w_h2[i];
  if (threadIdx.x < 32) {
    sBr[threadIdx.x] = b_rank[threadIdx.x];
    sB1[threadIdx.x] = b_h1[threadIdx.x];
    float cu = 0.f;
    for (int s2 = 4; s2 < 10; ++s2) cu += w_rank[threadIdx.x * 10 + s2];
    sCr[threadIdx.x] = cu;
  }
  if (threadIdx.x < 16) sB2[threadIdx.x] = b_h2[threadIdx.x];
  __syncthreads();
  const int tid = threadIdx.x;
  const int lane = tid & 63;
  const int y = lane & 3, k4 = lane >> 2;
  const int waveId = blockIdx.x * 4 + (tid >> 6);
  const int nW = gridDim.x * 4;
  float cbr[4], alr[4], ber[4], zbr[4], al1r[4], be1r[4];
#pragma unroll
  for (int rr = 0; rr < 4; ++rr) {
    const int k = k4 + 16 * rr;
    cbr[rr]  = conv_b[k];
    alr[rr]  = ws[WS_AL0 + k];
    ber[rr]  = ws[WS_BE0 + k];
    zbr[rr]  = ws[WS_ZBG + k];
    al1r[rr] = ws[WS_AL1 + k];
    be1r[rr] = ws[WS_BE1 + k];
  }
  float sAcc[4] = {0.f, 0.f, 0.f, 0.f}, ssAcc[4] = {0.f, 0.f, 0.f, 0.f};
  for (int m = waveId; m < M; m += nW) {
    int r[5], c[5];
    const int2* xp = (const int2*)(x + m * 10);
#pragma unroll
    for (int cc = 0; cc < 5; ++cc) { int2 t = xp[cc]; r[cc] = t.x; c[cc] = t.y; }
#pragma unroll
    for (int rr = 0; rr < 4; ++rr) {
      const int k = k4 + 16 * rr;
      const float* Wk = &sW[k * 81];
      const float al = alr[rr], be = ber[rr], zbg = zbr[rr], cb = cbr[rr];
      const float al1 = al1r[rr], be1 = be1r[rr];
      float a0[4];
#pragma unroll
      for (int xx = 0; xx < 4; ++xx) {
        float v = cb;
#pragma unroll
        for (int cc = 0; cc < 5; ++cc) {
          int di = r[cc] - y, dj = c[cc] - xx;
          if ((di | dj) >= 0) v += Wk[cc * 16 + di * 4 + dj];
        }
        a0[xx] = fmaxf(al * v + be, 0.f);
      }
      __builtin_amdgcn_sched_barrier(0);
      float r1[32];
#pragma unroll
      for (int o = 0; o < 32; ++o) {
        float acc = sBr[o] + zbg * sCr[o];
#pragma unroll
        for (int xx = 0; xx < 4; ++xx) acc += a0[xx] * sWr[o * 10 + xx];
        r1[o] = fmaxf(acc, 0.f);
      }
      __builtin_amdgcn_sched_barrier(0);
      float t2[16];
#pragma unroll
      for (int p = 0; p < 16; ++p) t2[p] = sB2[p];
#pragma unroll
      for (int ch = 0; ch < 4; ++ch) {
        float a1c[8];
#pragma unroll
        for (int u = 0; u < 8; ++u) {
          const int o = ch * 8 + u;
          float acc = sB1[o];
#pragma unroll
          for (int i = 0; i < 32; ++i) acc += r1[i] * sW1[o * 32 + i];
          a1c[u] = fmaxf(al1 * acc + be1, 0.f);
        }
        __builtin_amdgcn_sched_barrier(0);
#pragma unroll
        for (int p = 0; p < 16; ++p) {
          float acc = t2[p];
#pragma unroll
          for (int u = 0; u < 8; ++u) acc += a1c[u] * sW2[p * 32 + ch * 8 + u];
          t2[p] = acc;
        }
        __builtin_amdgcn_sched_barrier(0);
      }
      float s2l = 0.f, ss2l = 0.f;
#pragma unroll
      for (int p = 0; p < 16; ++p) { s2l += t2[p]; ss2l += t2[p] * t2[p]; }
      sAcc[rr] += s2l;
      ssAcc[rr] += ss2l;
    }
  }
#pragma unroll
  for (int rr = 0; rr < 4; ++rr) {
    float s = sAcc[rr], ss = ssAcc[rr];
    s  += __shfl_xor(s, 1);  s  += __shfl_xor(s, 2);
    ss += __shfl_xor(ss, 1); ss += __shfl_xor(ss, 2);
    if (y == 0) {
      atomicAdd(&ws[WS_SUM2 + k4 + 16 * rr], s);
      atomicAdd(&ws[WS_SSQ2 + k4 + 16 * rr], ss);
    }
  }
}

// ---------------------------------------------------------------------------
// Kernel 6: finalize BN2; background a2_bg; background output constant.
__global__ __launch_bounds__(64) void k_fin2(
    const float* __restrict__ g2, const float* __restrict__ b2,
    const float* __restrict__ w_out, const float* __restrict__ b_out,
    float* __restrict__ ws, int M) {
  __shared__ float red[64 * 9];
  const int k = threadIdx.x;
  const float n2 = (float)M * 11.f * 16.f;
  const float S = ws[WS_SUM2 + k], SS = ws[WS_SSQ2 + k];
  const float mu = S / n2;
  const float var = SS / n2 - mu * mu;
  const float rstd = rsqrtf(var + EPSV);
  const float al = rstd * g2[k];
  const float be = b2[k] - mu * al;
  ws[WS_AL2 + k] = al;
  ws[WS_BE2 + k] = be;
  float a2bg[16];
#pragma unroll
  for (int p = 0; p < 16; ++p) {
    a2bg[p] = fmaxf(al * ws[WS_T2BG + k * 16 + p] + be, 0.f);
    ws[WS_A2BG + k * 16 + p] = a2bg[p];
  }
  for (int j = 0; j < 9; ++j) {
    float acc = 0.f;
#pragma unroll
    for (int p = 0; p < 16; ++p) {
      float wsum = 0.f;
#pragma unroll
      for (int yy = 4; yy < 11; ++yy)
        wsum += w_out[j * 11264 + k * 176 + yy * 16 + p];
      acc += a2bg[p] * wsum;
    }
    red[k * 9 + j] = acc;
  }
  __syncthreads();
  if (k < 9) {
    float acc = b_out[k];
    for (int t = 0; t < 64; ++t) acc += red[t * 9 + k];
    ws[WS_OC + k] = acc;
  }
}

// ---------------------------------------------------------------------------
// Kernel 7: final. Wave-per-m, no block syncs; wave shuffle-reduce of po[9].
__global__ __launch_bounds__(256) void k_final(
    const int* __restrict__ x, const float* __restrict__ conv_w,
    const float* __restrict__ conv_b, const float* __restrict__ w_rank,
    const float* __restrict__ b_rank, const float* __restrict__ w_h1,
    const float* __restrict__ b_h1, const float* __restrict__ w_h2,
    const float* __restrict__ b_h2, const float* __restrict__ w_out,
    const float* __restrict__ ws, float* __restrict__ out, int M) {
  __shared__ float sW[CONV_LDS];
  __shared__ float sWr[320], sBr[32], sCr[32];
  __shared__ float sW1[1024], sB1[32];
  __shared__ float sW2[512], sB2[16];
  __shared__ float sOC[9];
  stage_conv(sW, conv_w, 256);
  for (int i = threadIdx.x; i < 320; i += 256) sWr[i] = w_rank[i];
  for (int i = threadIdx.x; i < 1024; i += 256) sW1[i] = w_h1[i];
  for (int i = threadIdx.x; i < 512; i += 256) sW2[i] = w_h2[i];
  if (threadIdx.x < 32) {
    sBr[threadIdx.x] = b_rank[threadIdx.x];
    sB1[threadIdx.x] = b_h1[threadIdx.x];
    float cu = 0.f;
    for (int s2 = 4; s2 < 10; ++s2) cu += w_rank[threadIdx.x * 10 + s2];
    sCr[threadIdx.x] = cu;
  }
  if (threadIdx.x < 16) sB2[threadIdx.x] = b_h2[threadIdx.x];
  if (threadIdx.x < 9) sOC[threadIdx.x] = ws[WS_OC + threadIdx.x];
  __syncthreads();
  const int tid = threadIdx.x;
  const int lane = tid & 63;
  const int y = lane & 3, k4 = lane >> 2;
  const int waveId = blockIdx.x * 4 + (tid >> 6);
  const int nW = gridDim.x * 4;
  float cbr[4], alr[4], ber[4], zbr[4], al1r[4], be1r[4], al2r[4], be2r[4];
#pragma unroll
  for (int rr = 0; rr < 4; ++rr) {
    const int k = k4 + 16 * rr;
    cbr[rr]  = conv_b[k];
    alr[rr]  = ws[WS_AL0 + k];
    ber[rr]  = ws[WS_BE0 + k];
    zbr[rr]  = ws[WS_ZBG + k];
    al1r[rr] = ws[WS_AL1 + k];
    be1r[rr] = ws[WS_BE1 + k];
    al2r[rr] = ws[WS_AL2 + k];
    be2r[rr] = ws[WS_BE2 + k];
  }
  for (int m = waveId; m < M; m += nW) {
    int r[5], c[5];
    const int2* xp = (const int2*)(x + m * 10);
#pragma unroll
    for (int cc = 0; cc < 5; ++cc) { int2 t = xp[cc]; r[cc] = t.x; c[cc] = t.y; }
    float po[9];
#pragma unroll
    for (int j = 0; j < 9; ++j) po[j] = 0.f;
#pragma unroll
    for (int rr = 0; rr < 4; ++rr) {
      const int k = k4 + 16 * rr;
      const float* Wk = &sW[k * 81];
      const float al = alr[rr], be = ber[rr], zbg = zbr[rr], cb = cbr[rr];
      const float al1 = al1r[rr], be1 = be1r[rr];
      const float al2 = al2r[rr], be2 = be2r[rr];
      float a0[4];
#pragma unroll
      for (int xx = 0; xx < 4; ++xx) {
        float v = cb;
#pragma unroll
        for (int cc = 0; cc < 5; ++cc) {
          int di = r[cc] - y, dj = c[cc] - xx;
          if ((di | dj) >= 0) v += Wk[cc * 16 + di * 4 + dj];
        }
        a0[xx] = fmaxf(al * v + be, 0.f);
      }
      __builtin_amdgcn_sched_barrier(0);
      float r1[32];
#pragma unroll
      for (int o = 0; o < 32; ++o) {
        float acc = sBr[o] + zbg * sCr[o];
#pragma unroll
        for (int xx = 0; xx < 4; ++xx) acc += a0[xx] * sWr[o * 10 + xx];
        r1[o] = fmaxf(acc, 0.f);
      }
      __builtin_amdgcn_sched_barrier(0);
      float t2[16];
#pragma unroll
      for (int p = 0; p < 16; ++p) t2[p] = sB2[p];
#pragma unroll
      for (int ch = 0; ch < 4; ++ch) {
        float a1c[8];
#pragma unroll
        for (int u = 0; u < 8; ++u) {
          const int o = ch * 8 + u;
          float acc = sB1[o];
#pragma unroll
          for (int i = 0; i < 32; ++i) acc += r1[i] * sW1[o * 32 + i];
          a1c[u] = fmaxf(al1 * acc + be1, 0.f);
        }
        __builtin_amdgcn_sched_barrier(0);
#pragma unroll
        for (int p = 0; p < 16; ++p) {
          float acc = t2[p];
#pragma unroll
          for (int u = 0; u < 8; ++u) acc += a1c[u] * sW2[p * 32 + ch * 8 + u];
          t2[p] = acc;
        }
        __builtin_amdgcn_sched_barrier(0);
      }
      float a2[16];
#pragma unroll
      for (int p = 0; p < 16; ++p) a2[p] = fmaxf(al2 * t2[p] + be2, 0.f);
      const float4* wo = (const float4*)(w_out + k * 176 + y * 16);
#pragma unroll
      for (int j = 0; j < 9; ++j) {
        float4 w0 = wo[j * 2816 + 0], w1 = wo[j * 2816 + 1];
        float4 w2 = wo[j * 2816 + 2], w3 = wo[j * 2816 + 3];
        po[j] += a2[0] * w0.x + a2[1] * w0.y + a2[2] * w0.z + a2[3] * w0.w
               + a2[4] * w1.x + a2[5] * w1.y + a2[6] * w1.z + a2[7] * w1.w
               + a2[8] * w2.x + a2[9] * w2.y + a2[10] * w2.z + a2[11] * w2.w
               + a2[12] * w3.x + a2[13] * w3.y + a2[14] * w3.z + a2[15] * w3.w;
      }
    }
#pragma unroll
    for (int j = 0; j < 9; ++j) {
      float v = po[j];
      v += __shfl_xor(v, 1);
      v += __shfl_xor(v, 2);
      v += __shfl_xor(v, 4);
      v += __shfl_xor(v, 8);
      v += __shfl_xor(v, 16);
      v += __shfl_xor(v, 32);
      po[j] = v;
    }
    if (lane == 0) {
#pragma unroll
      for (int j = 0; j < 9; ++j) out[m * 9 + j] = sOC[j] + po[j];
    }
  }
}

// ---------------------------------------------------------------------------
extern "C" void kernel_launch(void* const* d_in, const int* in_sizes, int n_in,
                              void* d_out, int out_size, void* d_ws, size_t ws_size,
                              hipStream_t stream) {
  const int*   x      = (const int*)d_in[0];
  const float* conv_w = (const float*)d_in[1];
  const float* conv_b = (const float*)d_in[2];
  const float* bn0_g  = (const float*)d_in[3];
  const float* bn0_b  = (const float*)d_in[4];
  const float* w_rank = (const float*)d_in[5];
  const float* b_rank = (const float*)d_in[6];
  const float* w_h1   = (const float*)d_in[7];
  const float* b_h1   = (const float*)d_in[8];
  const float* bn1_g  = (const float*)d_in[9];
  const float* bn1_b  = (const float*)d_in[10];
  const float* w_h2   = (const float*)d_in[11];
  const float* b_h2   = (const float*)d_in[12];
  const float* bn2_g  = (const float*)d_in[13];
  const float* bn2_b  = (const float*)d_in[14];
  const float* w_out  = (const float*)d_in[15];
  const float* b_out  = (const float*)d_in[16];
  float* out = (float*)d_out;
  float* ws  = (float*)d_ws;
  const int M = in_sizes[0] / 10;

  hipMemsetAsync(ws, 0, 384 * sizeof(float), stream);
  k_stats0<<<512, 256, 0, stream>>>(x, conv_w, conv_b, ws, M);
  k_fin0<<<1, 64, 0, stream>>>(conv_b, bn0_g, bn0_b, w_rank, b_rank, w_h1, b_h1, ws, M);
  k_stats1<<<1024, 256, 0, stream>>>(x, conv_w, conv_b, w_rank, b_rank, w_h1, b_h1, ws, M);
  k_fin1<<<1, 64, 0, stream>>>(bn1_g, bn1_b, w_h2, b_h2, ws, M);
  k_stats2<<<1024, 256, 0, stream>>>(x, conv_w, conv_b, w_rank, b_rank, w_h1, b_h1,
                                     w_h2, b_h2, ws, M);
  k_fin2<<<1, 64, 0, stream>>>(bn2_g, bn2_b, w_out, b_out, ws, M);
  k_final<<<1024, 256, 0, stream>>>(x, conv_w, conv_b, w_rank, b_rank, w_h1, b_h1,
                                    w_h2, b_h2, w_out, ws, out, M);
}

// Round 4
// 1107.321 us; speedup vs baseline: 7.3243x; 7.3243x over previous
//
#include <hip/hip_runtime.h>
#include <hip/hip_bf16.h>

#define EPSV 1e-5f

// workspace float offsets
#define WS_SUM0   0
#define WS_SSQ0   64
#define WS_SUM1   128
#define WS_SSQ1   192
#define WS_SUM2   256
#define WS_SSQ2   320
#define WS_AL0    384
#define WS_BE0    448
#define WS_ZBG    512
#define WS_T1BG   576      // 64*32
#define WS_AL1    2624
#define WS_BE1    2688
#define WS_T2BG   2752     // 64*16
#define WS_AL2    3776
#define WS_BE2    3840
#define WS_A2BG   3904     // 64*16
#define WS_OC     4928     // 9 used

// Repacked conv weights in LDS: only di,dj in [0,3] reachable (r,s <= 3).
// Layout: sW[k*81 + cc*16 + di*4 + dj]  (stride 81 -> odd vs 32 banks)
#define CONV_LDS 5184

__device__ __forceinline__ void stage_conv(float* sW, const float* __restrict__ conv_w,
                                           int nthr) {
  for (int i = threadIdx.x; i < 8000; i += nthr) {
    int k = i / 125, rem = i - k * 125;
    int cc = rem / 25, r2 = rem - cc * 25;
    int di = r2 / 5, dj = r2 - di * 5;
    if (di < 4 && dj < 4) sW[k * 81 + cc * 16 + di * 4 + dj] = conv_w[i];
  }
}

// ---------------------------------------------------------------------------
// Kernel 1: BN0 statistics over the active 16 conv positions (y<4, x<4).
__global__ __launch_bounds__(256) void k_stats0(
    const int* __restrict__ x, const float* __restrict__ conv_w,
    const float* __restrict__ conv_b, float* __restrict__ ws, int M) {
  __shared__ float sW[CONV_LDS];
  stage_conv(sW, conv_w, 256);
  __syncthreads();
  const int tid = threadIdx.x;
  const int mg = tid & 3;
  const int k  = tid >> 2;
  const float cb = conv_b[k];
  const float* Wk = &sW[k * 81];
  float s = 0.f, ss = 0.f;
  for (int m = blockIdx.x * 4 + mg; m < M; m += gridDim.x * 4) {
    int r[5], c[5];
    const int2* xp = (const int2*)(x + m * 10);
#pragma unroll
    for (int cc = 0; cc < 5; ++cc) { int2 t = xp[cc]; r[cc] = t.x; c[cc] = t.y; }
#pragma unroll
    for (int y = 0; y < 4; ++y) {
#pragma unroll
      for (int xx = 0; xx < 4; ++xx) {
        float v = cb;
#pragma unroll
        for (int cc = 0; cc < 5; ++cc) {
          int di = r[cc] - y, dj = c[cc] - xx;
          if ((di | dj) >= 0) v += Wk[cc * 16 + di * 4 + dj];
        }
        s += v;
        ss += v * v;
      }
      __builtin_amdgcn_sched_barrier(0);
    }
  }
  s  += __shfl_xor(s, 1);  s  += __shfl_xor(s, 2);
  ss += __shfl_xor(ss, 1); ss += __shfl_xor(ss, 2);
  if (mg == 0) {
    atomicAdd(&ws[WS_SUM0 + k], s);
    atomicAdd(&ws[WS_SSQ0 + k], ss);
  }
}

// ---------------------------------------------------------------------------
// Kernel 2: finalize BN0; background chain r1_bg -> t1_bg; seed BN1 stats.
__global__ __launch_bounds__(64) void k_fin0(
    const float* __restrict__ conv_b, const float* __restrict__ g0,
    const float* __restrict__ b0, const float* __restrict__ w_rank,
    const float* __restrict__ b_rank, const float* __restrict__ w_h1,
    const float* __restrict__ b_h1, float* __restrict__ ws, int M) {
  __shared__ float sS[32];
  const int t = threadIdx.x;
  if (t < 32) {
    float su = 0.f;
    for (int s2 = 0; s2 < 10; ++s2) su += w_rank[t * 10 + s2];
    sS[t] = su;
  }
  __syncthreads();
  const int k = t;
  const float n0 = 110.f * (float)M;
  const float cb = conv_b[k];
  const float S  = ws[WS_SUM0 + k] + 94.f * (float)M * cb;
  const float SS = ws[WS_SSQ0 + k] + 94.f * (float)M * cb * cb;
  const float mu = S / n0;
  const float var = SS / n0 - mu * mu;
  const float rstd = rsqrtf(var + EPSV);
  const float al = rstd * g0[k];
  const float be = b0[k] - mu * al;
  ws[WS_AL0 + k] = al;
  ws[WS_BE0 + k] = be;
  const float zbg = fmaxf(cb * al + be, 0.f);
  ws[WS_ZBG + k] = zbg;
  float r1bg[32];
#pragma unroll
  for (int o = 0; o < 32; ++o) r1bg[o] = fmaxf(zbg * sS[o] + b_rank[o], 0.f);
  float sb = 0.f, ssb = 0.f;
  for (int o = 0; o < 32; ++o) {
    float acc = b_h1[o];
#pragma unroll
    for (int i = 0; i < 32; ++i) acc += r1bg[i] * w_h1[o * 32 + i];
    ws[WS_T1BG + k * 32 + o] = acc;
    sb += acc;
    ssb += acc * acc;
  }
  ws[WS_SUM1 + k] = 7.f * (float)M * sb;
  ws[WS_SSQ1 + k] = 7.f * (float)M * ssb;
}

// ---------------------------------------------------------------------------
// Kernel 3: BN1 statistics. Block per m-PAIR; thread = (y=tid&3, k=tid>>2).
// Dual activations share every weight read; float4 LDS reads.
__global__ __launch_bounds__(256) void k_stats1(
    const int* __restrict__ x, const float* __restrict__ conv_w,
    const float* __restrict__ conv_b, const float* __restrict__ w_rank,
    const float* __restrict__ b_rank, const float* __restrict__ w_h1,
    const float* __restrict__ b_h1, float* __restrict__ ws, int M) {
  __shared__ float sW[CONV_LDS];
  __shared__ __align__(16) float sWra[128];   // [o][xx] active part of w_rank
  __shared__ float sBr[32], sCr[32];
  __shared__ __align__(16) float sW1[1024];
  __shared__ float sB1[32];
  stage_conv(sW, conv_w, 256);
  for (int i = threadIdx.x; i < 1024; i += 256) sW1[i] = w_h1[i];
  for (int i = threadIdx.x; i < 128; i += 256) sWra[i] = w_rank[(i >> 2) * 10 + (i & 3)];
  if (threadIdx.x < 32) {
    sBr[threadIdx.x] = b_rank[threadIdx.x];
    sB1[threadIdx.x] = b_h1[threadIdx.x];
    float cu = 0.f;
    for (int s2 = 4; s2 < 10; ++s2) cu += w_rank[threadIdx.x * 10 + s2];
    sCr[threadIdx.x] = cu;
  }
  __syncthreads();
  const int tid = threadIdx.x;
  const int y = tid & 3, k = tid >> 2;
  const float cb = conv_b[k];
  const float al = ws[WS_AL0 + k], be = ws[WS_BE0 + k], zbg = ws[WS_ZBG + k];
  const float* Wk = &sW[k * 81];
  const float4* sWrav = (const float4*)sWra;
  const float4* sW1v  = (const float4*)sW1;
  float sAcc = 0.f, ssAcc = 0.f;
  const int NP = (M + 1) >> 1;
  for (int mp = blockIdx.x; mp < NP; mp += gridDim.x) {
    const int m0 = mp * 2, m1 = m0 + 1;
    const bool hasB = (m1 < M);
    const int mB = hasB ? m1 : m0;
    int rA[5], cA[5], rBx[5], cBx[5];
    const int2* xpA = (const int2*)(x + m0 * 10);
    const int2* xpB = (const int2*)(x + mB * 10);
#pragma unroll
    for (int cc = 0; cc < 5; ++cc) {
      int2 tA = xpA[cc]; rA[cc] = tA.x; cA[cc] = tA.y;
      int2 tB = xpB[cc]; rBx[cc] = tB.x; cBx[cc] = tB.y;
    }
    float a0A[4], a0B[4];
#pragma unroll
    for (int xx = 0; xx < 4; ++xx) {
      float vA = cb, vB = cb;
#pragma unroll
      for (int cc = 0; cc < 5; ++cc) {
        int diA = rA[cc] - y, djA = cA[cc] - xx;
        if ((diA | djA) >= 0) vA += Wk[cc * 16 + diA * 4 + djA];
        int diB = rBx[cc] - y, djB = cBx[cc] - xx;
        if ((diB | djB) >= 0) vB += Wk[cc * 16 + diB * 4 + djB];
      }
      a0A[xx] = fmaxf(al * vA + be, 0.f);
      a0B[xx] = fmaxf(al * vB + be, 0.f);
    }
    __builtin_amdgcn_sched_barrier(0);
    float r1A[32], r1B[32];
#pragma unroll
    for (int o = 0; o < 32; ++o) {
      const float base = sBr[o] + zbg * sCr[o];
      float4 wr = sWrav[o];
      r1A[o] = fmaxf(base + a0A[0] * wr.x + a0A[1] * wr.y + a0A[2] * wr.z + a0A[3] * wr.w, 0.f);
      r1B[o] = fmaxf(base + a0B[0] * wr.x + a0B[1] * wr.y + a0B[2] * wr.z + a0B[3] * wr.w, 0.f);
    }
    __builtin_amdgcn_sched_barrier(0);
    float s1 = 0.f, ss1 = 0.f, s1B = 0.f, ss1B = 0.f;
#pragma unroll
    for (int ch = 0; ch < 4; ++ch) {
#pragma unroll
      for (int u = 0; u < 8; ++u) {
        const int o = ch * 8 + u;
        float accA = sB1[o], accB = accA;
#pragma unroll
        for (int iv = 0; iv < 8; ++iv) {
          float4 w4 = sW1v[o * 8 + iv];
          accA += r1A[iv * 4 + 0] * w4.x + r1A[iv * 4 + 1] * w4.y
                + r1A[iv * 4 + 2] * w4.z + r1A[iv * 4 + 3] * w4.w;
          accB += r1B[iv * 4 + 0] * w4.x + r1B[iv * 4 + 1] * w4.y
                + r1B[iv * 4 + 2] * w4.z + r1B[iv * 4 + 3] * w4.w;
        }
        s1 += accA;  ss1 += accA * accA;
        s1B += accB; ss1B += accB * accB;
      }
      __builtin_amdgcn_sched_barrier(0);
    }
    sAcc += s1;
    ssAcc += ss1;
    if (hasB) { sAcc += s1B; ssAcc += ss1B; }
  }
  sAcc  += __shfl_xor(sAcc, 1);  sAcc  += __shfl_xor(sAcc, 2);
  ssAcc += __shfl_xor(ssAcc, 1); ssAcc += __shfl_xor(ssAcc, 2);
  if (y == 0) {
    atomicAdd(&ws[WS_SUM1 + k], sAcc);
    atomicAdd(&ws[WS_SSQ1 + k], ssAcc);
  }
}

// ---------------------------------------------------------------------------
// Kernel 4: finalize BN1; background a1_bg -> t2_bg; seed BN2 stats.
__global__ __launch_bounds__(64) void k_fin1(
    const float* __restrict__ g1, const float* __restrict__ b1,
    const float* __restrict__ w_h2, const float* __restrict__ b_h2,
    float* __restrict__ ws, int M) {
  const int k = threadIdx.x;
  const float n1 = (float)M * 11.f * 32.f;
  const float S = ws[WS_SUM1 + k], SS = ws[WS_SSQ1 + k];
  const float mu = S / n1;
  const float var = SS / n1 - mu * mu;
  const float rstd = rsqrtf(var + EPSV);
  const float al = rstd * g1[k];
  const float be = b1[k] - mu * al;
  ws[WS_AL1 + k] = al;
  ws[WS_BE1 + k] = be;
  float a1bg[32];
#pragma unroll
  for (int o = 0; o < 32; ++o)
    a1bg[o] = fmaxf(al * ws[WS_T1BG + k * 32 + o] + be, 0.f);
  float sb = 0.f, ssb = 0.f;
  for (int p = 0; p < 16; ++p) {
    float acc = b_h2[p];
#pragma unroll
    for (int o = 0; o < 32; ++o) acc += a1bg[o] * w_h2[p * 32 + o];
    ws[WS_T2BG + k * 16 + p] = acc;
    sb += acc;
    ssb += acc * acc;
  }
  ws[WS_SUM2 + k] = 7.f * (float)M * sb;
  ws[WS_SSQ2 + k] = 7.f * (float)M * ssb;
}

// ---------------------------------------------------------------------------
// Kernel 5: BN2 statistics. Block per m-pair, chunked a1 -> t2, dual-m.
__global__ __launch_bounds__(256) void k_stats2(
    const int* __restrict__ x, const float* __restrict__ conv_w,
    const float* __restrict__ conv_b, const float* __restrict__ w_rank,
    const float* __restrict__ b_rank, const float* __restrict__ w_h1,
    const float* __restrict__ b_h1, const float* __restrict__ w_h2,
    const float* __restrict__ b_h2, float* __restrict__ ws, int M) {
  __shared__ float sW[CONV_LDS];
  __shared__ __align__(16) float sWra[128];
  __shared__ float sBr[32], sCr[32];
  __shared__ __align__(16) float sW1[1024];
  __shared__ float sB1[32];
  __shared__ __align__(16) float sW2[512];
  __shared__ float sB2[16];
  stage_conv(sW, conv_w, 256);
  for (int i = threadIdx.x; i < 1024; i += 256) sW1[i] = w_h1[i];
  for (int i = threadIdx.x; i < 512; i += 256) sW2[i] = w_h2[i];
  for (int i = threadIdx.x; i < 128; i += 256) sWra[i] = w_rank[(i >> 2) * 10 + (i & 3)];
  if (threadIdx.x < 32) {
    sBr[threadIdx.x] = b_rank[threadIdx.x];
    sB1[threadIdx.x] = b_h1[threadIdx.x];
    float cu = 0.f;
    for (int s2 = 4; s2 < 10; ++s2) cu += w_rank[threadIdx.x * 10 + s2];
    sCr[threadIdx.x] = cu;
  }
  if (threadIdx.x < 16) sB2[threadIdx.x] = b_h2[threadIdx.x];
  __syncthreads();
  const int tid = threadIdx.x;
  const int y = tid & 3, k = tid >> 2;
  const float cb = conv_b[k];
  const float al = ws[WS_AL0 + k], be = ws[WS_BE0 + k], zbg = ws[WS_ZBG + k];
  const float al1 = ws[WS_AL1 + k], be1 = ws[WS_BE1 + k];
  const float* Wk = &sW[k * 81];
  const float4* sWrav = (const float4*)sWra;
  const float4* sW1v  = (const float4*)sW1;
  const float4* sW2v  = (const float4*)sW2;
  float sAcc = 0.f, ssAcc = 0.f;
  const int NP = (M + 1) >> 1;
  for (int mp = blockIdx.x; mp < NP; mp += gridDim.x) {
    const int m0 = mp * 2, m1 = m0 + 1;
    const bool hasB = (m1 < M);
    const int mB = hasB ? m1 : m0;
    int rA[5], cA[5], rBx[5], cBx[5];
    const int2* xpA = (const int2*)(x + m0 * 10);
    const int2* xpB = (const int2*)(x + mB * 10);
#pragma unroll
    for (int cc = 0; cc < 5; ++cc) {
      int2 tA = xpA[cc]; rA[cc] = tA.x; cA[cc] = tA.y;
      int2 tB = xpB[cc]; rBx[cc] = tB.x; cBx[cc] = tB.y;
    }
    float a0A[4], a0B[4];
#pragma unroll
    for (int xx = 0; xx < 4; ++xx) {
      float vA = cb, vB = cb;
#pragma unroll
      for (int cc = 0; cc < 5; ++cc) {
        int diA = rA[cc] - y, djA = cA[cc] - xx;
        if ((diA | djA) >= 0) vA += Wk[cc * 16 + diA * 4 + djA];
        int diB = rBx[cc] - y, djB = cBx[cc] - xx;
        if ((diB | djB) >= 0) vB += Wk[cc * 16 + diB * 4 + djB];
      }
      a0A[xx] = fmaxf(al * vA + be, 0.f);
      a0B[xx] = fmaxf(al * vB + be, 0.f);
    }
    __builtin_amdgcn_sched_barrier(0);
    float r1A[32], r1B[32];
#pragma unroll
    for (int o = 0; o < 32; ++o) {
      const float base = sBr[o] + zbg * sCr[o];
      float4 wr = sWrav[o];
      r1A[o] = fmaxf(base + a0A[0] * wr.x + a0A[1] * wr.y + a0A[2] * wr.z + a0A[3] * wr.w, 0.f);
      r1B[o] = fmaxf(base + a0B[0] * wr.x + a0B[1] * wr.y + a0B[2] * wr.z + a0B[3] * wr.w, 0.f);
    }
    __builtin_amdgcn_sched_barrier(0);
    float tA[16], tB[16];
#pragma unroll
    for (int p = 0; p < 16; ++p) { tA[p] = sB2[p]; tB[p] = sB2[p]; }
#pragma unroll
    for (int ch = 0; ch < 4; ++ch) {
      float aA[8], aB[8];
#pragma unroll
      for (int u = 0; u < 8; ++u) {
        const int o = ch * 8 + u;
        float accA = sB1[o], accB = accA;
#pragma unroll
        for (int iv = 0; iv < 8; ++iv) {
          float4 w4 = sW1v[o * 8 + iv];
          accA += r1A[iv * 4 + 0] * w4.x + r1A[iv * 4 + 1] * w4.y
                + r1A[iv * 4 + 2] * w4.z + r1A[iv * 4 + 3] * w4.w;
          accB += r1B[iv * 4 + 0] * w4.x + r1B[iv * 4 + 1] * w4.y
                + r1B[iv * 4 + 2] * w4.z + r1B[iv * 4 + 3] * w4.w;
        }
        aA[u] = fmaxf(al1 * accA + be1, 0.f);
        aB[u] = fmaxf(al1 * accB + be1, 0.f);
      }
      __builtin_amdgcn_sched_barrier(0);
#pragma unroll
      for (int p = 0; p < 16; ++p) {
        float4 w40 = sW2v[p * 8 + ch * 2], w41 = sW2v[p * 8 + ch * 2 + 1];
        tA[p] += aA[0] * w40.x + aA[1] * w40.y + aA[2] * w40.z + aA[3] * w40.w
               + aA[4] * w41.x + aA[5] * w41.y + aA[6] * w41.z + aA[7] * w41.w;
        tB[p] += aB[0] * w40.x + aB[1] * w40.y + aB[2] * w40.z + aB[3] * w40.w
               + aB[4] * w41.x + aB[5] * w41.y + aB[6] * w41.z + aB[7] * w41.w;
      }
      __builtin_amdgcn_sched_barrier(0);
    }
    float sA2 = 0.f, ssA2 = 0.f, sB2a = 0.f, ssB2a = 0.f;
#pragma unroll
    for (int p = 0; p < 16; ++p) {
      sA2 += tA[p]; ssA2 += tA[p] * tA[p];
      sB2a += tB[p]; ssB2a += tB[p] * tB[p];
    }
    sAcc += sA2;
    ssAcc += ssA2;
    if (hasB) { sAcc += sB2a; ssAcc += ssB2a; }
  }
  sAcc  += __shfl_xor(sAcc, 1);  sAcc  += __shfl_xor(sAcc, 2);
  ssAcc += __shfl_xor(ssAcc, 1); ssAcc += __shfl_xor(ssAcc, 2);
  if (y == 0) {
    atomicAdd(&ws[WS_SUM2 + k], sAcc);
    atomicAdd(&ws[WS_SSQ2 + k], ssAcc);
  }
}

// ---------------------------------------------------------------------------
// Kernel 6: finalize BN2; background a2_bg; background output constant.
__global__ __launch_bounds__(64) void k_fin2(
    const float* __restrict__ g2, const float* __restrict__ b2,
    const float* __restrict__ w_out, const float* __restrict__ b_out,
    float* __restrict__ ws, int M) {
  __shared__ float red[64 * 9];
  const int k = threadIdx.x;
  const float n2 = (float)M * 11.f * 16.f;
  const float S = ws[WS_SUM2 + k], SS = ws[WS_SSQ2 + k];
  const float mu = S / n2;
  const float var = SS / n2 - mu * mu;
  const float rstd = rsqrtf(var + EPSV);
  const float al = rstd * g2[k];
  const float be = b2[k] - mu * al;
  ws[WS_AL2 + k] = al;
  ws[WS_BE2 + k] = be;
  float a2bg[16];
#pragma unroll
  for (int p = 0; p < 16; ++p) {
    a2bg[p] = fmaxf(al * ws[WS_T2BG + k * 16 + p] + be, 0.f);
    ws[WS_A2BG + k * 16 + p] = a2bg[p];
  }
  for (int j = 0; j < 9; ++j) {
    float acc = 0.f;
#pragma unroll
    for (int p = 0; p < 16; ++p) {
      float wsum = 0.f;
#pragma unroll
      for (int yy = 4; yy < 11; ++yy)
        wsum += w_out[j * 11264 + k * 176 + yy * 16 + p];
      acc += a2bg[p] * wsum;
    }
    red[k * 9 + j] = acc;
  }
  __syncthreads();
  if (k < 9) {
    float acc = b_out[k];
    for (int t = 0; t < 64; ++t) acc += red[t * 9 + k];
    ws[WS_OC + k] = acc;
  }
}

// ---------------------------------------------------------------------------
// Kernel 7: final. Block per m-pair, dual-m chain, one sync per pair.
__global__ __launch_bounds__(256) void k_final(
    const int* __restrict__ x, const float* __restrict__ conv_w,
    const float* __restrict__ conv_b, const float* __restrict__ w_rank,
    const float* __restrict__ b_rank, const float* __restrict__ w_h1,
    const float* __restrict__ b_h1, const float* __restrict__ w_h2,
    const float* __restrict__ b_h2, const float* __restrict__ w_out,
    const float* __restrict__ ws, float* __restrict__ out, int M) {
  __shared__ float sW[CONV_LDS];
  __shared__ __align__(16) float sWra[128];
  __shared__ float sBr[32], sCr[32];
  __shared__ __align__(16) float sW1[1024];
  __shared__ float sB1[32];
  __shared__ __align__(16) float sW2[512];
  __shared__ float sB2[16];
  __shared__ float sOC[9];
  __shared__ float sRedA[4][9], sRedB[4][9];
  stage_conv(sW, conv_w, 256);
  for (int i = threadIdx.x; i < 1024; i += 256) sW1[i] = w_h1[i];
  for (int i = threadIdx.x; i < 512; i += 256) sW2[i] = w_h2[i];
  for (int i = threadIdx.x; i < 128; i += 256) sWra[i] = w_rank[(i >> 2) * 10 + (i & 3)];
  if (threadIdx.x < 32) {
    sBr[threadIdx.x] = b_rank[threadIdx.x];
    sB1[threadIdx.x] = b_h1[threadIdx.x];
    float cu = 0.f;
    for (int s2 = 4; s2 < 10; ++s2) cu += w_rank[threadIdx.x * 10 + s2];
    sCr[threadIdx.x] = cu;
  }
  if (threadIdx.x < 16) sB2[threadIdx.x] = b_h2[threadIdx.x];
  if (threadIdx.x < 9) sOC[threadIdx.x] = ws[WS_OC + threadIdx.x];
  __syncthreads();
  const int tid = threadIdx.x;
  const int lane = tid & 63, wv = tid >> 6;
  const int y = tid & 3, k = tid >> 2;
  const float cb = conv_b[k];
  const float al = ws[WS_AL0 + k], be = ws[WS_BE0 + k], zbg = ws[WS_ZBG + k];
  const float al1 = ws[WS_AL1 + k], be1 = ws[WS_BE1 + k];
  const float al2 = ws[WS_AL2 + k], be2 = ws[WS_BE2 + k];
  const float* Wk = &sW[k * 81];
  const float4* sWrav = (const float4*)sWra;
  const float4* sW1v  = (const float4*)sW1;
  const float4* sW2v  = (const float4*)sW2;
  const float4* wo = (const float4*)(w_out + k * 176 + y * 16);
  const int NP = (M + 1) >> 1;
  bool first = true;
  for (int mp = blockIdx.x; mp < NP; mp += gridDim.x) {
    if (!first) __syncthreads();   // protect sRed reuse across iterations
    first = false;
    const int m0 = mp * 2, m1 = m0 + 1;
    const bool hasB = (m1 < M);
    const int mB = hasB ? m1 : m0;
    int rA[5], cA[5], rBx[5], cBx[5];
    const int2* xpA = (const int2*)(x + m0 * 10);
    const int2* xpB = (const int2*)(x + mB * 10);
#pragma unroll
    for (int cc = 0; cc < 5; ++cc) {
      int2 tA = xpA[cc]; rA[cc] = tA.x; cA[cc] = tA.y;
      int2 tB = xpB[cc]; rBx[cc] = tB.x; cBx[cc] = tB.y;
    }
    float a0A[4], a0B[4];
#pragma unroll
    for (int xx = 0; xx < 4; ++xx) {
      float vA = cb, vB = cb;
#pragma unroll
      for (int cc = 0; cc < 5; ++cc) {
        int diA = rA[cc] - y, djA = cA[cc] - xx;
        if ((diA | djA) >= 0) vA += Wk[cc * 16 + diA * 4 + djA];
        int diB = rBx[cc] - y, djB = cBx[cc] - xx;
        if ((diB | djB) >= 0) vB += Wk[cc * 16 + diB * 4 + djB];
      }
      a0A[xx] = fmaxf(al * vA + be, 0.f);
      a0B[xx] = fmaxf(al * vB + be, 0.f);
    }
    __builtin_amdgcn_sched_barrier(0);
    float r1A[32], r1B[32];
#pragma unroll
    for (int o = 0; o < 32; ++o) {
      const float base = sBr[o] + zbg * sCr[o];
      float4 wr = sWrav[o];
      r1A[o] = fmaxf(base + a0A[0] * wr.x + a0A[1] * wr.y + a0A[2] * wr.z + a0A[3] * wr.w, 0.f);
      r1B[o] = fmaxf(base + a0B[0] * wr.x + a0B[1] * wr.y + a0B[2] * wr.z + a0B[3] * wr.w, 0.f);
    }
    __builtin_amdgcn_sched_barrier(0);
    float tA[16], tB[16];
#pragma unroll
    for (int p = 0; p < 16; ++p) { tA[p] = sB2[p]; tB[p] = sB2[p]; }
#pragma unroll
    for (int ch = 0; ch < 4; ++ch) {
      float aA[8], aB[8];
#pragma unroll
      for (int u = 0; u < 8; ++u) {
        const int o = ch * 8 + u;
        float accA = sB1[o], accB = accA;
#pragma unroll
        for (int iv = 0; iv < 8; ++iv) {
          float4 w4 = sW1v[o * 8 + iv];
          accA += r1A[iv * 4 + 0] * w4.x + r1A[iv * 4 + 1] * w4.y
                + r1A[iv * 4 + 2] * w4.z + r1A[iv * 4 + 3] * w4.w;
          accB += r1B[iv * 4 + 0] * w4.x + r1B[iv * 4 + 1] * w4.y
                + r1B[iv * 4 + 2] * w4.z + r1B[iv * 4 + 3] * w4.w;
        }
        aA[u] = fmaxf(al1 * accA + be1, 0.f);
        aB[u] = fmaxf(al1 * accB + be1, 0.f);
      }
      __builtin_amdgcn_sched_barrier(0);
#pragma unroll
      for (int p = 0; p < 16; ++p) {
        float4 w40 = sW2v[p * 8 + ch * 2], w41 = sW2v[p * 8 + ch * 2 + 1];
        tA[p] += aA[0] * w40.x + aA[1] * w40.y + aA[2] * w40.z + aA[3] * w40.w
               + aA[4] * w41.x + aA[5] * w41.y + aA[6] * w41.z + aA[7] * w41.w;
        tB[p] += aB[0] * w40.x + aB[1] * w40.y + aB[2] * w40.z + aB[3] * w40.w
               + aB[4] * w41.x + aB[5] * w41.y + aB[6] * w41.z + aB[7] * w41.w;
      }
      __builtin_amdgcn_sched_barrier(0);
    }
    float a2A[16], a2B[16];
#pragma unroll
    for (int p = 0; p < 16; ++p) {
      a2A[p] = fmaxf(al2 * tA[p] + be2, 0.f);
      a2B[p] = fmaxf(al2 * tB[p] + be2, 0.f);
    }
    float poA[9], poB[9];
#pragma unroll
    for (int j = 0; j < 9; ++j) {
      float4 w0 = wo[j * 2816 + 0], w1 = wo[j * 2816 + 1];
      float4 w2 = wo[j * 2816 + 2], w3 = wo[j * 2816 + 3];
      poA[j] = a2A[0] * w0.x + a2A[1] * w0.y + a2A[2] * w0.z + a2A[3] * w0.w
             + a2A[4] * w1.x + a2A[5] * w1.y + a2A[6] * w1.z + a2A[7] * w1.w
             + a2A[8] * w2.x + a2A[9] * w2.y + a2A[10] * w2.z + a2A[11] * w2.w
             + a2A[12] * w3.x + a2A[13] * w3.y + a2A[14] * w3.z + a2A[15] * w3.w;
      poB[j] = a2B[0] * w0.x + a2B[1] * w0.y + a2B[2] * w0.z + a2B[3] * w0.w
             + a2B[4] * w1.x + a2B[5] * w1.y + a2B[6] * w1.z + a2B[7] * w1.w
             + a2B[8] * w2.x + a2B[9] * w2.y + a2B[10] * w2.z + a2B[11] * w2.w
             + a2B[12] * w3.x + a2B[13] * w3.y + a2B[14] * w3.z + a2B[15] * w3.w;
    }
#pragma unroll
    for (int j = 0; j < 9; ++j) {
      float vA = poA[j], vB = poB[j];
      vA += __shfl_xor(vA, 1);  vB += __shfl_xor(vB, 1);
      vA += __shfl_xor(vA, 2);  vB += __shfl_xor(vB, 2);
      vA += __shfl_xor(vA, 4);  vB += __shfl_xor(vB, 4);
      vA += __shfl_xor(vA, 8);  vB += __shfl_xor(vB, 8);
      vA += __shfl_xor(vA, 16); vB += __shfl_xor(vB, 16);
      vA += __shfl_xor(vA, 32); vB += __shfl_xor(vB, 32);
      poA[j] = vA; poB[j] = vB;
    }
    if (lane == 0) {
#pragma unroll
      for (int j = 0; j < 9; ++j) { sRedA[wv][j] = poA[j]; sRedB[wv][j] = poB[j]; }
    }
    __syncthreads();
    if (tid < 9) {
      float acc = sOC[tid];
#pragma unroll
      for (int w2i = 0; w2i < 4; ++w2i) acc += sRedA[w2i][tid];
      out[m0 * 9 + tid] = acc;
    } else if (tid >= 64 && tid < 73 && hasB) {
      const int j = tid - 64;
      float acc = sOC[j];
#pragma unroll
      for (int w2i = 0; w2i < 4; ++w2i) acc += sRedB[w2i][j];
      out[m1 * 9 + j] = acc;
    }
  }
}

// ---------------------------------------------------------------------------
extern "C" void kernel_launch(void* const* d_in, const int* in_sizes, int n_in,
                              void* d_out, int out_size, void* d_ws, size_t ws_size,
                              hipStream_t stream) {
  const int*   x      = (const int*)d_in[0];
  const float* conv_w = (const float*)d_in[1];
  const float* conv_b = (const float*)d_in[2];
  const float* bn0_g  = (const float*)d_in[3];
  const float* bn0_b  = (const float*)d_in[4];
  const float* w_rank = (const float*)d_in[5];
  const float* b_rank = (const float*)d_in[6];
  const float* w_h1   = (const float*)d_in[7];
  const float* b_h1   = (const float*)d_in[8];
  const float* bn1_g  = (const float*)d_in[9];
  const float* bn1_b  = (const float*)d_in[10];
  const float* w_h2   = (const float*)d_in[11];
  const float* b_h2   = (const float*)d_in[12];
  const float* bn2_g  = (const float*)d_in[13];
  const float* bn2_b  = (const float*)d_in[14];
  const float* w_out  = (const float*)d_in[15];
  const float* b_out  = (const float*)d_in[16];
  float* out = (float*)d_out;
  float* ws  = (float*)d_ws;
  const int M = in_sizes[0] / 10;
  const int NP = (M + 1) >> 1;
  const int grid = NP < 2048 ? NP : 2048;

  hipMemsetAsync(ws, 0, 384 * sizeof(float), stream);
  k_stats0<<<512, 256, 0, stream>>>(x, conv_w, conv_b, ws, M);
  k_fin0<<<1, 64, 0, stream>>>(conv_b, bn0_g, bn0_b, w_rank, b_rank, w_h1, b_h1, ws, M);
  k_stats1<<<grid, 256, 0, stream>>>(x, conv_w, conv_b, w_rank, b_rank, w_h1, b_h1, ws, M);
  k_fin1<<<1, 64, 0, stream>>>(bn1_g, bn1_b, w_h2, b_h2, ws, M);
  k_stats2<<<grid, 256, 0, stream>>>(x, conv_w, conv_b, w_rank, b_rank, w_h1, b_h1,
                                     w_h2, b_h2, ws, M);
  k_fin2<<<1, 64, 0, stream>>>(bn2_g, bn2_b, w_out, b_out, ws, M);
  k_final<<<grid, 256, 0, stream>>>(x, conv_w, conv_b, w_rank, b_rank, w_h1, b_h1,
                                    w_h2, b_h2, w_out, ws, out, M);
}

// Round 5
// 560.682 us; speedup vs baseline: 14.4652x; 1.9750x over previous
//
#include <hip/hip_runtime.h>
#include <hip/hip_bf16.h>

#define EPSV 1e-5f

// workspace float offsets
#define WS_SUM0   0
#define WS_SSQ0   64
#define WS_SUM1   128
#define WS_SSQ1   192
#define WS_SUM2   256
#define WS_SSQ2   320
#define WS_AL0    384
#define WS_BE0    448
#define WS_ZBG    512
#define WS_T1BG   576      // 64*32
#define WS_AL1    2624
#define WS_BE1    2688
#define WS_T2BG   2752     // 64*16
#define WS_AL2    3776
#define WS_BE2    3840
#define WS_A2BG   3904     // 64*16
#define WS_OC     4928     // 9 used

// Repacked conv weights in LDS: only di,dj in [0,3] reachable (r,s <= 3).
// Layout: sW[k*81 + cc*16 + di*4 + dj]  (stride 81 -> odd vs 32 banks)
#define CONV_LDS 5184

__device__ __forceinline__ void stage_conv(float* sW, const float* __restrict__ conv_w,
                                           int nthr) {
  for (int i = threadIdx.x; i < 8000; i += nthr) {
    int k = i / 125, rem = i - k * 125;
    int cc = rem / 25, r2 = rem - cc * 25;
    int di = r2 / 5, dj = r2 - di * 5;
    if (di < 4 && dj < 4) sW[k * 81 + cc * 16 + di * 4 + dj] = conv_w[i];
  }
}

// ---------------------------------------------------------------------------
// Kernel 1: BN0 statistics over the active 16 conv positions (y<4, x<4).
__global__ __launch_bounds__(256) void k_stats0(
    const int* __restrict__ x, const float* __restrict__ conv_w,
    const float* __restrict__ conv_b, float* __restrict__ ws, int M) {
  __shared__ float sW[CONV_LDS];
  stage_conv(sW, conv_w, 256);
  __syncthreads();
  const int tid = threadIdx.x;
  const int mg = tid & 3;
  const int k  = tid >> 2;
  const float cb = conv_b[k];
  const float* Wk = &sW[k * 81];
  float s = 0.f, ss = 0.f;
  for (int m = blockIdx.x * 4 + mg; m < M; m += gridDim.x * 4) {
    int r[5], c[5];
    const int2* xp = (const int2*)(x + m * 10);
#pragma unroll
    for (int cc = 0; cc < 5; ++cc) { int2 t = xp[cc]; r[cc] = t.x; c[cc] = t.y; }
#pragma unroll
    for (int y = 0; y < 4; ++y) {
#pragma unroll
      for (int xx = 0; xx < 4; ++xx) {
        float v = cb;
#pragma unroll
        for (int cc = 0; cc < 5; ++cc) {
          int di = r[cc] - y, dj = c[cc] - xx;
          if ((di | dj) >= 0) v += Wk[cc * 16 + di * 4 + dj];
        }
        s += v;
        ss += v * v;
      }
      __builtin_amdgcn_sched_barrier(0);
    }
  }
  s  += __shfl_xor(s, 1);  s  += __shfl_xor(s, 2);
  ss += __shfl_xor(ss, 1); ss += __shfl_xor(ss, 2);
  if (mg == 0) {
    atomicAdd(&ws[WS_SUM0 + k], s);
    atomicAdd(&ws[WS_SSQ0 + k], ss);
  }
}

// ---------------------------------------------------------------------------
// Kernel 2: finalize BN0; background chain r1_bg -> t1_bg; seed BN1 stats.
__global__ __launch_bounds__(64) void k_fin0(
    const float* __restrict__ conv_b, const float* __restrict__ g0,
    const float* __restrict__ b0, const float* __restrict__ w_rank,
    const float* __restrict__ b_rank, const float* __restrict__ w_h1,
    const float* __restrict__ b_h1, float* __restrict__ ws, int M) {
  __shared__ float sS[32];
  const int t = threadIdx.x;
  if (t < 32) {
    float su = 0.f;
    for (int s2 = 0; s2 < 10; ++s2) su += w_rank[t * 10 + s2];
    sS[t] = su;
  }
  __syncthreads();
  const int k = t;
  const float n0 = 110.f * (float)M;
  const float cb = conv_b[k];
  const float S  = ws[WS_SUM0 + k] + 94.f * (float)M * cb;
  const float SS = ws[WS_SSQ0 + k] + 94.f * (float)M * cb * cb;
  const float mu = S / n0;
  const float var = SS / n0 - mu * mu;
  const float rstd = rsqrtf(var + EPSV);
  const float al = rstd * g0[k];
  const float be = b0[k] - mu * al;
  ws[WS_AL0 + k] = al;
  ws[WS_BE0 + k] = be;
  const float zbg = fmaxf(cb * al + be, 0.f);
  ws[WS_ZBG + k] = zbg;
  float r1bg[32];
#pragma unroll
  for (int o = 0; o < 32; ++o) r1bg[o] = fmaxf(zbg * sS[o] + b_rank[o], 0.f);
  float sb = 0.f, ssb = 0.f;
  for (int o = 0; o < 32; ++o) {
    float acc = b_h1[o];
#pragma unroll
    for (int i = 0; i < 32; ++i) acc += r1bg[i] * w_h1[o * 32 + i];
    ws[WS_T1BG + k * 32 + o] = acc;
    sb += acc;
    ssb += acc * acc;
  }
  ws[WS_SUM1 + k] = 7.f * (float)M * sb;
  ws[WS_SSQ1 + k] = 7.f * (float)M * ssb;
}

// ---------------------------------------------------------------------------
// Kernel 3: BN1 statistics. Block per m (grid-stride); thread=(y,k).
// Single-m live state; float4 LDS weight reads.
__global__ __launch_bounds__(256) void k_stats1(
    const int* __restrict__ x, const float* __restrict__ conv_w,
    const float* __restrict__ conv_b, const float* __restrict__ w_rank,
    const float* __restrict__ b_rank, const float* __restrict__ w_h1,
    const float* __restrict__ b_h1, float* __restrict__ ws, int M) {
  __shared__ float sW[CONV_LDS];
  __shared__ __align__(16) float sWra[128];   // [o][xx] active part of w_rank
  __shared__ float sBr[32], sCr[32];
  __shared__ __align__(16) float sW1[1024];
  __shared__ float sB1[32];
  stage_conv(sW, conv_w, 256);
  for (int i = threadIdx.x; i < 1024; i += 256) sW1[i] = w_h1[i];
  for (int i = threadIdx.x; i < 128; i += 256) sWra[i] = w_rank[(i >> 2) * 10 + (i & 3)];
  if (threadIdx.x < 32) {
    sBr[threadIdx.x] = b_rank[threadIdx.x];
    sB1[threadIdx.x] = b_h1[threadIdx.x];
    float cu = 0.f;
    for (int s2 = 4; s2 < 10; ++s2) cu += w_rank[threadIdx.x * 10 + s2];
    sCr[threadIdx.x] = cu;
  }
  __syncthreads();
  const int tid = threadIdx.x;
  const int y = tid & 3, k = tid >> 2;
  const float cb = conv_b[k];
  const float al = ws[WS_AL0 + k], be = ws[WS_BE0 + k], zbg = ws[WS_ZBG + k];
  const float* Wk = &sW[k * 81];
  const float4* sWrav = (const float4*)sWra;
  const float4* sW1v  = (const float4*)sW1;
  float sAcc = 0.f, ssAcc = 0.f;
  for (int m = blockIdx.x; m < M; m += gridDim.x) {
    int r[5], c[5];
    const int2* xp = (const int2*)(x + m * 10);
#pragma unroll
    for (int cc = 0; cc < 5; ++cc) { int2 t = xp[cc]; r[cc] = t.x; c[cc] = t.y; }
    float a0[4];
#pragma unroll
    for (int xx = 0; xx < 4; ++xx) {
      float v = cb;
#pragma unroll
      for (int cc = 0; cc < 5; ++cc) {
        int di = r[cc] - y, dj = c[cc] - xx;
        if ((di | dj) >= 0) v += Wk[cc * 16 + di * 4 + dj];
      }
      a0[xx] = fmaxf(al * v + be, 0.f);
    }
    __builtin_amdgcn_sched_barrier(0);
    float r1[32];
#pragma unroll
    for (int o = 0; o < 32; ++o) {
      float4 wr = sWrav[o];
      r1[o] = fmaxf(sBr[o] + zbg * sCr[o]
                    + a0[0] * wr.x + a0[1] * wr.y + a0[2] * wr.z + a0[3] * wr.w, 0.f);
    }
    __builtin_amdgcn_sched_barrier(0);
    float s1 = 0.f, ss1 = 0.f;
#pragma unroll
    for (int ch = 0; ch < 4; ++ch) {
#pragma unroll
      for (int u = 0; u < 8; ++u) {
        const int o = ch * 8 + u;
        float acc = sB1[o];
#pragma unroll
        for (int iv = 0; iv < 8; ++iv) {
          float4 w4 = sW1v[o * 8 + iv];
          acc += r1[iv * 4 + 0] * w4.x + r1[iv * 4 + 1] * w4.y
               + r1[iv * 4 + 2] * w4.z + r1[iv * 4 + 3] * w4.w;
        }
        s1 += acc;
        ss1 += acc * acc;
      }
      __builtin_amdgcn_sched_barrier(0);
    }
    sAcc += s1;
    ssAcc += ss1;
  }
  sAcc  += __shfl_xor(sAcc, 1);  sAcc  += __shfl_xor(sAcc, 2);
  ssAcc += __shfl_xor(ssAcc, 1); ssAcc += __shfl_xor(ssAcc, 2);
  if (y == 0) {
    atomicAdd(&ws[WS_SUM1 + k], sAcc);
    atomicAdd(&ws[WS_SSQ1 + k], ssAcc);
  }
}

// ---------------------------------------------------------------------------
// Kernel 4: finalize BN1; background a1_bg -> t2_bg; seed BN2 stats.
__global__ __launch_bounds__(64) void k_fin1(
    const float* __restrict__ g1, const float* __restrict__ b1,
    const float* __restrict__ w_h2, const float* __restrict__ b_h2,
    float* __restrict__ ws, int M) {
  const int k = threadIdx.x;
  const float n1 = (float)M * 11.f * 32.f;
  const float S = ws[WS_SUM1 + k], SS = ws[WS_SSQ1 + k];
  const float mu = S / n1;
  const float var = SS / n1 - mu * mu;
  const float rstd = rsqrtf(var + EPSV);
  const float al = rstd * g1[k];
  const float be = b1[k] - mu * al;
  ws[WS_AL1 + k] = al;
  ws[WS_BE1 + k] = be;
  float a1bg[32];
#pragma unroll
  for (int o = 0; o < 32; ++o)
    a1bg[o] = fmaxf(al * ws[WS_T1BG + k * 32 + o] + be, 0.f);
  float sb = 0.f, ssb = 0.f;
  for (int p = 0; p < 16; ++p) {
    float acc = b_h2[p];
#pragma unroll
    for (int o = 0; o < 32; ++o) acc += a1bg[o] * w_h2[p * 32 + o];
    ws[WS_T2BG + k * 16 + p] = acc;
    sb += acc;
    ssb += acc * acc;
  }
  ws[WS_SUM2 + k] = 7.f * (float)M * sb;
  ws[WS_SSQ2 + k] = 7.f * (float)M * ssb;
}

// ---------------------------------------------------------------------------
// Kernel 5: BN2 statistics. Block per m, chunked a1 -> t2, float4 reads.
__global__ __launch_bounds__(256) void k_stats2(
    const int* __restrict__ x, const float* __restrict__ conv_w,
    const float* __restrict__ conv_b, const float* __restrict__ w_rank,
    const float* __restrict__ b_rank, const float* __restrict__ w_h1,
    const float* __restrict__ b_h1, const float* __restrict__ w_h2,
    const float* __restrict__ b_h2, float* __restrict__ ws, int M) {
  __shared__ float sW[CONV_LDS];
  __shared__ __align__(16) float sWra[128];
  __shared__ float sBr[32], sCr[32];
  __shared__ __align__(16) float sW1[1024];
  __shared__ float sB1[32];
  __shared__ __align__(16) float sW2[512];
  __shared__ float sB2[16];
  stage_conv(sW, conv_w, 256);
  for (int i = threadIdx.x; i < 1024; i += 256) sW1[i] = w_h1[i];
  for (int i = threadIdx.x; i < 512; i += 256) sW2[i] = w_h2[i];
  for (int i = threadIdx.x; i < 128; i += 256) sWra[i] = w_rank[(i >> 2) * 10 + (i & 3)];
  if (threadIdx.x < 32) {
    sBr[threadIdx.x] = b_rank[threadIdx.x];
    sB1[threadIdx.x] = b_h1[threadIdx.x];
    float cu = 0.f;
    for (int s2 = 4; s2 < 10; ++s2) cu += w_rank[threadIdx.x * 10 + s2];
    sCr[threadIdx.x] = cu;
  }
  if (threadIdx.x < 16) sB2[threadIdx.x] = b_h2[threadIdx.x];
  __syncthreads();
  const int tid = threadIdx.x;
  const int y = tid & 3, k = tid >> 2;
  const float cb = conv_b[k];
  const float al = ws[WS_AL0 + k], be = ws[WS_BE0 + k], zbg = ws[WS_ZBG + k];
  const float al1 = ws[WS_AL1 + k], be1 = ws[WS_BE1 + k];
  const float* Wk = &sW[k * 81];
  const float4* sWrav = (const float4*)sWra;
  const float4* sW1v  = (const float4*)sW1;
  const float4* sW2v  = (const float4*)sW2;
  float sAcc = 0.f, ssAcc = 0.f;
  for (int m = blockIdx.x; m < M; m += gridDim.x) {
    int r[5], c[5];
    const int2* xp = (const int2*)(x + m * 10);
#pragma unroll
    for (int cc = 0; cc < 5; ++cc) { int2 t = xp[cc]; r[cc] = t.x; c[cc] = t.y; }
    float a0[4];
#pragma unroll
    for (int xx = 0; xx < 4; ++xx) {
      float v = cb;
#pragma unroll
      for (int cc = 0; cc < 5; ++cc) {
        int di = r[cc] - y, dj = c[cc] - xx;
        if ((di | dj) >= 0) v += Wk[cc * 16 + di * 4 + dj];
      }
      a0[xx] = fmaxf(al * v + be, 0.f);
    }
    __builtin_amdgcn_sched_barrier(0);
    float r1[32];
#pragma unroll
    for (int o = 0; o < 32; ++o) {
      float4 wr = sWrav[o];
      r1[o] = fmaxf(sBr[o] + zbg * sCr[o]
                    + a0[0] * wr.x + a0[1] * wr.y + a0[2] * wr.z + a0[3] * wr.w, 0.f);
    }
    __builtin_amdgcn_sched_barrier(0);
    float t2[16];
#pragma unroll
    for (int p = 0; p < 16; ++p) t2[p] = sB2[p];
#pragma unroll
    for (int ch = 0; ch < 4; ++ch) {
      float a1c[8];
#pragma unroll
      for (int u = 0; u < 8; ++u) {
        const int o = ch * 8 + u;
        float acc = sB1[o];
#pragma unroll
        for (int iv = 0; iv < 8; ++iv) {
          float4 w4 = sW1v[o * 8 + iv];
          acc += r1[iv * 4 + 0] * w4.x + r1[iv * 4 + 1] * w4.y
               + r1[iv * 4 + 2] * w4.z + r1[iv * 4 + 3] * w4.w;
        }
        a1c[u] = fmaxf(al1 * acc + be1, 0.f);
      }
      __builtin_amdgcn_sched_barrier(0);
#pragma unroll
      for (int p = 0; p < 16; ++p) {
        float4 w40 = sW2v[p * 8 + ch * 2], w41 = sW2v[p * 8 + ch * 2 + 1];
        t2[p] += a1c[0] * w40.x + a1c[1] * w40.y + a1c[2] * w40.z + a1c[3] * w40.w
               + a1c[4] * w41.x + a1c[5] * w41.y + a1c[6] * w41.z + a1c[7] * w41.w;
      }
      __builtin_amdgcn_sched_barrier(0);
    }
    float s2l = 0.f, ss2l = 0.f;
#pragma unroll
    for (int p = 0; p < 16; ++p) { s2l += t2[p]; ss2l += t2[p] * t2[p]; }
    sAcc += s2l;
    ssAcc += ss2l;
  }
  sAcc  += __shfl_xor(sAcc, 1);  sAcc  += __shfl_xor(sAcc, 2);
  ssAcc += __shfl_xor(ssAcc, 1); ssAcc += __shfl_xor(ssAcc, 2);
  if (y == 0) {
    atomicAdd(&ws[WS_SUM2 + k], sAcc);
    atomicAdd(&ws[WS_SSQ2 + k], ssAcc);
  }
}

// ---------------------------------------------------------------------------
// Kernel 6: finalize BN2; background a2_bg; background output constant.
__global__ __launch_bounds__(64) void k_fin2(
    const float* __restrict__ g2, const float* __restrict__ b2,
    const float* __restrict__ w_out, const float* __restrict__ b_out,
    float* __restrict__ ws, int M) {
  __shared__ float red[64 * 9];
  const int k = threadIdx.x;
  const float n2 = (float)M * 11.f * 16.f;
  const float S = ws[WS_SUM2 + k], SS = ws[WS_SSQ2 + k];
  const float mu = S / n2;
  const float var = SS / n2 - mu * mu;
  const float rstd = rsqrtf(var + EPSV);
  const float al = rstd * g2[k];
  const float be = b2[k] - mu * al;
  ws[WS_AL2 + k] = al;
  ws[WS_BE2 + k] = be;
  float a2bg[16];
#pragma unroll
  for (int p = 0; p < 16; ++p) {
    a2bg[p] = fmaxf(al * ws[WS_T2BG + k * 16 + p] + be, 0.f);
    ws[WS_A2BG + k * 16 + p] = a2bg[p];
  }
  for (int j = 0; j < 9; ++j) {
    float acc = 0.f;
#pragma unroll
    for (int p = 0; p < 16; ++p) {
      float wsum = 0.f;
#pragma unroll
      for (int yy = 4; yy < 11; ++yy)
        wsum += w_out[j * 11264 + k * 176 + yy * 16 + p];
      acc += a2bg[p] * wsum;
    }
    red[k * 9 + j] = acc;
  }
  __syncthreads();
  if (k < 9) {
    float acc = b_out[k];
    for (int t = 0; t < 64; ++t) acc += red[t * 9 + k];
    ws[WS_OC + k] = acc;
  }
}

// ---------------------------------------------------------------------------
// Kernel 7: final. Block per m, single-m chain, float4 reads, 2 syncs per m.
__global__ __launch_bounds__(256) void k_final(
    const int* __restrict__ x, const float* __restrict__ conv_w,
    const float* __restrict__ conv_b, const float* __restrict__ w_rank,
    const float* __restrict__ b_rank, const float* __restrict__ w_h1,
    const float* __restrict__ b_h1, const float* __restrict__ w_h2,
    const float* __restrict__ b_h2, const float* __restrict__ w_out,
    const float* __restrict__ ws, float* __restrict__ out, int M) {
  __shared__ float sW[CONV_LDS];
  __shared__ __align__(16) float sWra[128];
  __shared__ float sBr[32], sCr[32];
  __shared__ __align__(16) float sW1[1024];
  __shared__ float sB1[32];
  __shared__ __align__(16) float sW2[512];
  __shared__ float sB2[16];
  __shared__ float sOC[9];
  __shared__ float sRed[4][9];
  stage_conv(sW, conv_w, 256);
  for (int i = threadIdx.x; i < 1024; i += 256) sW1[i] = w_h1[i];
  for (int i = threadIdx.x; i < 512; i += 256) sW2[i] = w_h2[i];
  for (int i = threadIdx.x; i < 128; i += 256) sWra[i] = w_rank[(i >> 2) * 10 + (i & 3)];
  if (threadIdx.x < 32) {
    sBr[threadIdx.x] = b_rank[threadIdx.x];
    sB1[threadIdx.x] = b_h1[threadIdx.x];
    float cu = 0.f;
    for (int s2 = 4; s2 < 10; ++s2) cu += w_rank[threadIdx.x * 10 + s2];
    sCr[threadIdx.x] = cu;
  }
  if (threadIdx.x < 16) sB2[threadIdx.x] = b_h2[threadIdx.x];
  if (threadIdx.x < 9) sOC[threadIdx.x] = ws[WS_OC + threadIdx.x];
  __syncthreads();
  const int tid = threadIdx.x;
  const int lane = tid & 63, wv = tid >> 6;
  const int y = tid & 3, k = tid >> 2;
  const float cb = conv_b[k];
  const float al = ws[WS_AL0 + k], be = ws[WS_BE0 + k], zbg = ws[WS_ZBG + k];
  const float al1 = ws[WS_AL1 + k], be1 = ws[WS_BE1 + k];
  const float al2 = ws[WS_AL2 + k], be2 = ws[WS_BE2 + k];
  const float* Wk = &sW[k * 81];
  const float4* sWrav = (const float4*)sWra;
  const float4* sW1v  = (const float4*)sW1;
  const float4* sW2v  = (const float4*)sW2;
  const float4* wo = (const float4*)(w_out + k * 176 + y * 16);
  bool first = true;
  for (int m = blockIdx.x; m < M; m += gridDim.x) {
    if (!first) __syncthreads();   // protect sRed reuse across iterations
    first = false;
    int r[5], c[5];
    const int2* xp = (const int2*)(x + m * 10);
#pragma unroll
    for (int cc = 0; cc < 5; ++cc) { int2 t = xp[cc]; r[cc] = t.x; c[cc] = t.y; }
    float a0[4];
#pragma unroll
    for (int xx = 0; xx < 4; ++xx) {
      float v = cb;
#pragma unroll
      for (int cc = 0; cc < 5; ++cc) {
        int di = r[cc] - y, dj = c[cc] - xx;
        if ((di | dj) >= 0) v += Wk[cc * 16 + di * 4 + dj];
      }
      a0[xx] = fmaxf(al * v + be, 0.f);
    }
    __builtin_amdgcn_sched_barrier(0);
    float r1[32];
#pragma unroll
    for (int o = 0; o < 32; ++o) {
      float4 wr = sWrav[o];
      r1[o] = fmaxf(sBr[o] + zbg * sCr[o]
                    + a0[0] * wr.x + a0[1] * wr.y + a0[2] * wr.z + a0[3] * wr.w, 0.f);
    }
    __builtin_amdgcn_sched_barrier(0);
    float t2[16];
#pragma unroll
    for (int p = 0; p < 16; ++p) t2[p] = sB2[p];
#pragma unroll
    for (int ch = 0; ch < 4; ++ch) {
      float a1c[8];
#pragma unroll
      for (int u = 0; u < 8; ++u) {
        const int o = ch * 8 + u;
        float acc = sB1[o];
#pragma unroll
        for (int iv = 0; iv < 8; ++iv) {
          float4 w4 = sW1v[o * 8 + iv];
          acc += r1[iv * 4 + 0] * w4.x + r1[iv * 4 + 1] * w4.y
               + r1[iv * 4 + 2] * w4.z + r1[iv * 4 + 3] * w4.w;
        }
        a1c[u] = fmaxf(al1 * acc + be1, 0.f);
      }
      __builtin_amdgcn_sched_barrier(0);
#pragma unroll
      for (int p = 0; p < 16; ++p) {
        float4 w40 = sW2v[p * 8 + ch * 2], w41 = sW2v[p * 8 + ch * 2 + 1];
        t2[p] += a1c[0] * w40.x + a1c[1] * w40.y + a1c[2] * w40.z + a1c[3] * w40.w
               + a1c[4] * w41.x + a1c[5] * w41.y + a1c[6] * w41.z + a1c[7] * w41.w;
      }
      __builtin_amdgcn_sched_barrier(0);
    }
    float a2[16];
#pragma unroll
    for (int p = 0; p < 16; ++p) a2[p] = fmaxf(al2 * t2[p] + be2, 0.f);
    float po[9];
#pragma unroll
    for (int j = 0; j < 9; ++j) {
      float4 w0 = wo[j * 2816 + 0], w1 = wo[j * 2816 + 1];
      float4 w2 = wo[j * 2816 + 2], w3 = wo[j * 2816 + 3];
      po[j] = a2[0] * w0.x + a2[1] * w0.y + a2[2] * w0.z + a2[3] * w0.w
            + a2[4] * w1.x + a2[5] * w1.y + a2[6] * w1.z + a2[7] * w1.w
            + a2[8] * w2.x + a2[9] * w2.y + a2[10] * w2.z + a2[11] * w2.w
            + a2[12] * w3.x + a2[13] * w3.y + a2[14] * w3.z + a2[15] * w3.w;
    }
#pragma unroll
    for (int j = 0; j < 9; ++j) {
      float v = po[j];
      v += __shfl_xor(v, 1);
      v += __shfl_xor(v, 2);
      v += __shfl_xor(v, 4);
      v += __shfl_xor(v, 8);
      v += __shfl_xor(v, 16);
      v += __shfl_xor(v, 32);
      po[j] = v;
    }
    if (lane == 0) {
#pragma unroll
      for (int j = 0; j < 9; ++j) sRed[wv][j] = po[j];
    }
    __syncthreads();
    if (tid < 9) {
      float acc = sOC[tid];
#pragma unroll
      for (int w2i = 0; w2i < 4; ++w2i) acc += sRed[w2i][tid];
      out[m * 9 + tid] = acc;
    }
  }
}

// ---------------------------------------------------------------------------
extern "C" void kernel_launch(void* const* d_in, const int* in_sizes, int n_in,
                              void* d_out, int out_size, void* d_ws, size_t ws_size,
                              hipStream_t stream) {
  const int*   x      = (const int*)d_in[0];
  const float* conv_w = (const float*)d_in[1];
  const float* conv_b = (const float*)d_in[2];
  const float* bn0_g  = (const float*)d_in[3];
  const float* bn0_b  = (const float*)d_in[4];
  const float* w_rank = (const float*)d_in[5];
  const float* b_rank = (const float*)d_in[6];
  const float* w_h1   = (const float*)d_in[7];
  const float* b_h1   = (const float*)d_in[8];
  const float* bn1_g  = (const float*)d_in[9];
  const float* bn1_b  = (const float*)d_in[10];
  const float* w_h2   = (const float*)d_in[11];
  const float* b_h2   = (const float*)d_in[12];
  const float* bn2_g  = (const float*)d_in[13];
  const float* bn2_b  = (const float*)d_in[14];
  const float* w_out  = (const float*)d_in[15];
  const float* b_out  = (const float*)d_in[16];
  float* out = (float*)d_out;
  float* ws  = (float*)d_ws;
  const int M = in_sizes[0] / 10;

  hipMemsetAsync(ws, 0, 384 * sizeof(float), stream);
  k_stats0<<<512, 256, 0, stream>>>(x, conv_w, conv_b, ws, M);
  k_fin0<<<1, 64, 0, stream>>>(conv_b, bn0_g, bn0_b, w_rank, b_rank, w_h1, b_h1, ws, M);
  k_stats1<<<1024, 256, 0, stream>>>(x, conv_w, conv_b, w_rank, b_rank, w_h1, b_h1, ws, M);
  k_fin1<<<1, 64, 0, stream>>>(bn1_g, bn1_b, w_h2, b_h2, ws, M);
  k_stats2<<<1024, 256, 0, stream>>>(x, conv_w, conv_b, w_rank, b_rank, w_h1, b_h1,
                                     w_h2, b_h2, ws, M);
  k_fin2<<<1, 64, 0, stream>>>(bn2_g, bn2_b, w_out, b_out, ws, M);
  k_final<<<1024, 256, 0, stream>>>(x, conv_w, conv_b, w_rank, b_rank, w_h1, b_h1,
                                    w_h2, b_h2, w_out, ws, out, M);
}